// Round 2
// baseline (500.818 us; speedup 1.0000x reference)
//
#include <hip/hip_runtime.h>

// z[b,d] = x[b,d] * (1 + sum_{i=1..K} w[i-1,d] * x[b,(d+i) mod D])
// B=8192, D=4096, K=16, fp32. HBM-bound: ideal ~268 MB traffic -> ~43 us floor.
// R1: burst-staged LDS tiles via global_load_lds to fix latency-bound R0
// (1.6 TB/s, 5 loads in flight/wave). 8 rows/block staged in one burst.

#define D 4096
#define DG 1024          // D/4 float4 column-groups per row
#define K 16
#define TPB 256
#define TILE_B 8
#define ROW_F4 260       // 256 groups + 4 halo groups (16 halo floats)
#define ROW_F (ROW_F4 * 4)

__global__ __launch_bounds__(TPB, 4) void quad_enhancer_kernel(
    const float* __restrict__ x, const float* __restrict__ w,
    float* __restrict__ out) {
  __shared__ float lds[TILE_B * ROW_F];  // 33280 B -> 4 blocks/CU

  const int tid = threadIdx.x;
  const int cg0 = blockIdx.x * TPB;  // first column-group of this stripe
  const int cg = cg0 + tid;          // this thread's column-group (0..1023)
  const int b0 = blockIdx.y * TILE_B;

  // w[:, 4cg..4cg+3] cached in registers, reused for all TILE_B rows.
  const float4* w4 = (const float4*)w;
  float4 wv[K];
#pragma unroll
  for (int i = 0; i < K; ++i) wv[i] = w4[i * DG + cg];

  const float4* x4 = (const float4*)x;

  // ---- burst-stage TILE_B rows into LDS (async, no VGPR round-trip) ----
  // LDS dest per wave is base + lane*16: tid-linear layout satisfies the
  // wave-uniform-base constraint of global_load_lds.
#pragma unroll
  for (int r = 0; r < TILE_B; ++r) {
    const float4* gptr = &x4[(size_t)(b0 + r) * DG + cg];
    float* lptr = &lds[r * ROW_F + tid * 4];
    __builtin_amdgcn_global_load_lds(
        (const __attribute__((address_space(1))) void*)gptr,
        (__attribute__((address_space(3))) void*)lptr, 16, 0, 0);
  }
  // Halo: 4 float4 per row (wrap mod D); 32 lanes cover all 8 rows.
  // (Not lane-linear in LDS -> must use plain load + ds_write.)
  if (tid < TILE_B * 4) {
    const int r = tid >> 2, j = tid & 3;
    float4 h = x4[(size_t)(b0 + r) * DG + ((cg0 + 256 + j) & (DG - 1))];
    *(float4*)&lds[r * ROW_F + (256 + j) * 4] = h;
  }
  __syncthreads();  // drains vmcnt (incl. global_load_lds) + lgkmcnt

  float4* out4 = (float4*)out;
#pragma unroll 2
  for (int r = 0; r < TILE_B; ++r) {
    const float4* lrow = (const float4*)&lds[r * ROW_F];
    float xs[20];
#pragma unroll
    for (int j = 0; j < 5; ++j) {  // 5 x ds_read_b128, consecutive lanes
      float4 v = lrow[tid + j];
      xs[4 * j + 0] = v.x;
      xs[4 * j + 1] = v.y;
      xs[4 * j + 2] = v.z;
      xs[4 * j + 3] = v.w;
    }
    float ax = 1.0f, ay = 1.0f, az = 1.0f, aw = 1.0f;
#pragma unroll
    for (int i = 0; i < K; ++i) {
      ax = fmaf(wv[i].x, xs[i + 1], ax);
      ay = fmaf(wv[i].y, xs[i + 2], ay);
      az = fmaf(wv[i].z, xs[i + 3], az);
      aw = fmaf(wv[i].w, xs[i + 4], aw);
    }
    float4 o;
    o.x = xs[0] * ax;
    o.y = xs[1] * ay;
    o.z = xs[2] * az;
    o.w = xs[3] * aw;
    out4[(size_t)(b0 + r) * DG + cg] = o;
  }
}

extern "C" void kernel_launch(void* const* d_in, const int* in_sizes, int n_in,
                              void* d_out, int out_size, void* d_ws, size_t ws_size,
                              hipStream_t stream) {
  const float* x = (const float*)d_in[0];
  const float* w = (const float*)d_in[1];
  float* out = (float*)d_out;
  const int B = in_sizes[0] / D;  // 8192

  dim3 grid(DG / TPB, B / TILE_B);  // (4, 1024) = 4096 blocks
  quad_enhancer_kernel<<<grid, TPB, 0, stream>>>(x, w, out);
}

// Round 3
// 235.690 us; speedup vs baseline: 2.1249x; 2.1249x over previous
//
#include <hip/hip_runtime.h>

// z[b,d] = x[b,d] * (1 + sum_{i=1..K} w[i-1,d] * x[b,(d+i) mod D])
// B=8192, D=4096, K=16, fp32. HBM-bound: ideal ~268 MB traffic -> ~43 us floor.
// R1 lesson: __launch_bounds__(256,4) clamped VGPR to 64 -> wv[16]+xs[20]
// spilled to scratch -> 900 MB of HBM spill traffic, 352 us. R2: same burst
// LDS staging, no register clamp (compiler picks ~110-128, no spill).

#define D 4096
#define DG 1024          // D/4 float4 column-groups per row
#define K 16
#define TPB 256
#define TILE_B 8
#define ROW_F4 260       // 256 groups + 4 halo groups (16 halo floats)
#define ROW_F (ROW_F4 * 4)

__global__ __launch_bounds__(TPB) void quad_enhancer_kernel(
    const float* __restrict__ x, const float* __restrict__ w,
    float* __restrict__ out) {
  __shared__ float lds[TILE_B * ROW_F];  // 33280 B -> 4 blocks/CU

  const int tid = threadIdx.x;
  const int cg0 = blockIdx.x * TPB;  // first column-group of this stripe
  const int cg = cg0 + tid;          // this thread's column-group (0..1023)
  const int b0 = blockIdx.y * TILE_B;

  const float4* x4 = (const float4*)x;

  // ---- burst-stage TILE_B rows into LDS first (long-latency HBM loads,
  // async, no VGPR round-trip; 8 KB/wave in flight) ----
#pragma unroll
  for (int r = 0; r < TILE_B; ++r) {
    const float4* gptr = &x4[(size_t)(b0 + r) * DG + cg];
    float* lptr = &lds[r * ROW_F + tid * 4];
    __builtin_amdgcn_global_load_lds(
        (const __attribute__((address_space(1))) void*)gptr,
        (__attribute__((address_space(3))) void*)lptr, 16, 0, 0);
  }
  // Halo: 4 float4 per row (wrap mod D); 32 lanes cover all 8 rows.
  float4 halo;
  int hr = 0, hj = 0;
  if (tid < TILE_B * 4) {
    hr = tid >> 2;
    hj = tid & 3;
    halo = x4[(size_t)(b0 + hr) * DG + ((cg0 + 256 + hj) & (DG - 1))];
  }

  // w[:, 4cg..4cg+3] cached in registers (64 VGPRs), reused all TILE_B rows.
  // These are L2/L3-hot (w is 256 KB, read by every block).
  const float4* w4 = (const float4*)w;
  float4 wv[K];
#pragma unroll
  for (int i = 0; i < K; ++i) wv[i] = w4[i * DG + cg];

  if (tid < TILE_B * 4) {
    *(float4*)&lds[hr * ROW_F + (256 + hj) * 4] = halo;
  }
  __syncthreads();  // drains vmcnt (incl. global_load_lds) + lgkmcnt

  float4* out4 = (float4*)out;
#pragma unroll 2
  for (int r = 0; r < TILE_B; ++r) {
    const float4* lrow = (const float4*)&lds[r * ROW_F];
    float xs[20];
#pragma unroll
    for (int j = 0; j < 5; ++j) {  // 5 x ds_read_b128, consecutive lanes
      float4 v = lrow[tid + j];
      xs[4 * j + 0] = v.x;
      xs[4 * j + 1] = v.y;
      xs[4 * j + 2] = v.z;
      xs[4 * j + 3] = v.w;
    }
    float ax = 1.0f, ay = 1.0f, az = 1.0f, aw = 1.0f;
#pragma unroll
    for (int i = 0; i < K; ++i) {
      ax = fmaf(wv[i].x, xs[i + 1], ax);
      ay = fmaf(wv[i].y, xs[i + 2], ay);
      az = fmaf(wv[i].z, xs[i + 3], az);
      aw = fmaf(wv[i].w, xs[i + 4], aw);
    }
    float4 o;
    o.x = xs[0] * ax;
    o.y = xs[1] * ay;
    o.z = xs[2] * az;
    o.w = xs[3] * aw;
    out4[(size_t)(b0 + r) * DG + cg] = o;
  }
}

extern "C" void kernel_launch(void* const* d_in, const int* in_sizes, int n_in,
                              void* d_out, int out_size, void* d_ws, size_t ws_size,
                              hipStream_t stream) {
  const float* x = (const float*)d_in[0];
  const float* w = (const float*)d_in[1];
  float* out = (float*)d_out;
  const int B = in_sizes[0] / D;  // 8192

  dim3 grid(DG / TPB, B / TILE_B);  // (4, 1024) = 4096 blocks
  quad_enhancer_kernel<<<grid, TPB, 0, stream>>>(x, w, out);
}